// Round 10
// baseline (2219.995 us; speedup 1.0000x reference)
//
#include <hip/hip_runtime.h>
#include <hip/hip_bf16.h>

// ---------------- problem dims ----------------
#define TT 40
#define BB 64
#define LL 80
#define DD 256
#define HH 1024
#define G4H 4096
#define AA 18
#define KENC 1280   // [demo(256) | h(1024)]
#define KLSTM 2048  // [x(1024) | h(1024)]
#define KCOMB 1280  // [attn(1024) | obs(256)]
#define NB 256
#define NT 1024
#define QSZ (TT*BB*AA)

typedef __bf16 bf16x8 __attribute__((ext_vector_type(8)));
typedef float  f32x4  __attribute__((ext_vector_type(4)));

// ---------------- workspace layout (bytes) ----------------
#define OFF_WENC   ((size_t)0)
#define OFF_WLSTM  (OFF_WENC  + (size_t)G4H*KENC*2)
#define OFF_WCOMB  (OFF_WLSTM + (size_t)G4H*KLSTM*2)
#define OFF_WMID   (OFF_WCOMB + (size_t)HH*KCOMB*2)
#define OFF_BIASE  (OFF_WMID  + (size_t)HH*HH*2)
#define OFF_BIASL  (OFF_BIASE + (size_t)G4H*4)
#define OFF_DEMO   (OFF_BIASL + (size_t)G4H*4)
#define OFF_STATE  (OFF_DEMO  + (size_t)BB*LL*DD*2)
#define OFF_ENC    (OFF_STATE + (size_t)TT*BB*DD*2)
#define OFF_HDEC   (OFF_ENC   + (size_t)BB*LL*HH*2)
#define OFF_XALL   (OFF_HDEC  + (size_t)TT*BB*HH*2)
#define OFF_MF     (OFF_XALL  + (size_t)TT*BB*HH*2)
#define OFF_ATTNS  (OFF_MF    + (size_t)TT*BB*HH*2)
#define OFF_HROT   (OFF_ATTNS + (size_t)BB*HH*2)
#define NSLOT_E    81
#define NSLOT_D    41
#define OFF_BAR    (OFF_HROT  + (size_t)(NSLOT_E+NSLOT_D)*BB*HH*2)
#define FLAG_STRIDE 16          // dwords: 64B per flag
#define BAR_BYTES  (NB*FLAG_STRIDE*4)

// ---------------- helpers ----------------
__device__ __forceinline__ float sigm(float x){ return 1.f/(1.f+__expf(-x)); }

__device__ __forceinline__ float wred_sum(float v){
#pragma unroll
  for (int s=32; s>0; s>>=1) v += __shfl_xor(v, s, 64);
  return v;
}
__device__ __forceinline__ float wred_max(float v){
#pragma unroll
  for (int s=32; s>0; s>>=1) v = fmaxf(v, __shfl_xor(v, s, 64));
  return v;
}
__device__ __forceinline__ unsigned pack_bf16(float a, float b){
  unsigned short ua = __builtin_bit_cast(unsigned short, (__bf16)a);
  unsigned short ub = __builtin_bit_cast(unsigned short, (__bf16)b);
  return (unsigned)ua | ((unsigned)ub << 16);
}

// write-through (coherent) stores: visible at MALL, never stale in any L2
__device__ __forceinline__ void st_u32_sc(unsigned* p, unsigned v){
  __hip_atomic_store(p, v, __ATOMIC_RELAXED, __HIP_MEMORY_SCOPE_AGENT);
}
__device__ __forceinline__ void st_b16_sc(__bf16* p, float v){
  unsigned short u = __builtin_bit_cast(unsigned short, (__bf16)v);
  asm volatile("global_store_short %0, %1, off sc0 sc1"
               :: "v"(p), "v"((unsigned)u) : "memory");
}

// split all-to-all flag barrier (no same-address contention, no invalidations)
__device__ __forceinline__ void gbar_arrive(unsigned* flags, unsigned target, int bk){
  __syncthreads();   // drains vmcnt -> this block's stores done
  if (threadIdx.x == 0) {
    __builtin_amdgcn_fence(__ATOMIC_RELEASE, "agent");
    __hip_atomic_store(flags + (size_t)bk*FLAG_STRIDE, target,
                       __ATOMIC_RELAXED, __HIP_MEMORY_SCOPE_AGENT);
  }
}
__device__ __forceinline__ void gbar_wait(unsigned* flags, unsigned target){
  if (threadIdx.x < 64) {
    unsigned long long spins = 0;
    for (;;) {
      unsigned a0 = __hip_atomic_load(flags + (size_t)threadIdx.x*FLAG_STRIDE,       __ATOMIC_RELAXED, __HIP_MEMORY_SCOPE_AGENT);
      unsigned a1 = __hip_atomic_load(flags + (size_t)(64+threadIdx.x)*FLAG_STRIDE,  __ATOMIC_RELAXED, __HIP_MEMORY_SCOPE_AGENT);
      unsigned a2 = __hip_atomic_load(flags + (size_t)(128+threadIdx.x)*FLAG_STRIDE, __ATOMIC_RELAXED, __HIP_MEMORY_SCOPE_AGENT);
      unsigned a3 = __hip_atomic_load(flags + (size_t)(192+threadIdx.x)*FLAG_STRIDE, __ATOMIC_RELAXED, __HIP_MEMORY_SCOPE_AGENT);
      bool ok = (a0 >= target) && (a1 >= target) && (a2 >= target) && (a3 >= target);
      if (__all((int)ok)) break;
      if (++spins > (1ull<<20)) break;   // fail loud, never hang
      __builtin_amdgcn_s_sleep(1);
    }
  }
  __syncthreads();
  asm volatile("" ::: "memory");
}

// ---------------- fused prologue (one dispatch) ----------------
// [0,4096) pack enc | [4096,8192) pack lstm | [8192,13312) comb
// [13312,17408) mid | [17408,22528) demo | [22528,25088) state
// [25088,25104) zero flags
#define PB1 4096
#define PB2 8192
#define PB3 13312
#define PB4 17408
#define PB5 22528
#define PB6 25088
#define PGRID 25104
__global__ __launch_bounds__(256)
void k_prep(const float* __restrict__ enc_wih, const float* __restrict__ enc_whh,
            const float* __restrict__ enc_bih, const float* __restrict__ enc_bhh,
            const float* __restrict__ lstm_wih, const float* __restrict__ lstm_whh,
            const float* __restrict__ lstm_bih, const float* __restrict__ lstm_bhh,
            const float* __restrict__ comb_w, const float* __restrict__ mid_w,
            const float* __restrict__ demo, const float* __restrict__ state,
            char* __restrict__ ws){
  int blk = blockIdx.x, tid = threadIdx.x;
  if (blk < PB1) {                    // pack enc gate rows
    int p = blk;
    int gate = p & 3, jj = (p >> 2) & 3, bq = p >> 4;
    int orig = gate*HH + bq*4 + jj;
    if (tid == 0) ((float*)(ws + OFF_BIASE))[p] = enc_bih[orig] + enc_bhh[orig];
    const float* s0 = enc_wih + (size_t)orig*DD;
    const float* s1 = enc_whh + (size_t)orig*HH;
    __bf16* d = (__bf16*)(ws + OFF_WENC) + (size_t)p*KENC;
    for (int k = tid; k < KENC; k += 256)
      d[k] = (__bf16)(k < DD ? s0[k] : s1[k-DD]);
  } else if (blk < PB2) {             // pack lstm gate rows
    int p = blk - PB1;
    int gate = p & 3, jj = (p >> 2) & 3, bq = p >> 4;
    int orig = gate*HH + bq*4 + jj;
    if (tid == 0) ((float*)(ws + OFF_BIASL))[p] = lstm_bih[orig] + lstm_bhh[orig];
    const float* s0 = lstm_wih + (size_t)orig*HH;
    const float* s1 = lstm_whh + (size_t)orig*HH;
    __bf16* d = (__bf16*)(ws + OFF_WLSTM) + (size_t)p*KLSTM;
    for (int k = tid; k < KLSTM; k += 256)
      d[k] = (__bf16)(k < HH ? s0[k] : s1[k-HH]);
  } else if (blk < PB3) {             // comb
    int i = (blk - PB2)*256 + tid;
    ((__bf16*)(ws + OFF_WCOMB))[i] = (__bf16)comb_w[i];
  } else if (blk < PB4) {             // mid
    int i = (blk - PB3)*256 + tid;
    ((__bf16*)(ws + OFF_WMID))[i] = (__bf16)mid_w[i];
  } else if (blk < PB5) {             // demo
    int i = (blk - PB4)*256 + tid;
    ((__bf16*)(ws + OFF_DEMO))[i] = (__bf16)demo[i];
  } else if (blk < PB6) {             // state
    int i = (blk - PB5)*256 + tid;
    ((__bf16*)(ws + OFF_STATE))[i] = (__bf16)state[i];
  } else {                            // zero barrier flags (each replay)
    int i = (blk - PB6)*256 + tid;
    ((unsigned*)(ws + OFF_BAR))[i] = 0u;
  }
}

// ---------------- persistent main kernel ----------------
// 16 waves/block = (mt 0-3) x (kq 0-3). Block bk owns 16 packed gate rows.
// K-walk start is ROTATED per block ((bk>>3) stagger) so the 32 blocks on an
// XCD fetch DISJOINT lines of the fresh h/x buffers concurrently (the R4-R9
// ~15us/phase floor was duplicate-line lockstep fill).
__global__ __launch_bounds__(NT, 1)
void k_main(const int* __restrict__ demlen,
            const float* __restrict__ h0, const float* __restrict__ c0,
            const float* __restrict__ attn_w,
            const float* __restrict__ comb_b, const float* __restrict__ mid_b,
            const float* __restrict__ out_w, const float* __restrict__ out_b,
            float* __restrict__ out, char* __restrict__ ws){
  const int bk = blockIdx.x, tid = threadIdx.x;
  const int wv = tid >> 6, ln = tid & 63;
  const int l15 = ln & 15, lhi = ln >> 4;
  const int klane = lhi * 8;
  const int gtid = bk*NT + tid;

  __bf16* wEnc  = (__bf16*)(ws + OFF_WENC);
  __bf16* wLstm = (__bf16*)(ws + OFF_WLSTM);
  __bf16* wComb = (__bf16*)(ws + OFF_WCOMB);
  __bf16* wMid  = (__bf16*)(ws + OFF_WMID);
  const float* bE = (const float*)(ws + OFF_BIASE);
  const float* bL = (const float*)(ws + OFF_BIASL);
  __bf16* demoC = (__bf16*)(ws + OFF_DEMO);
  __bf16* stateB= (__bf16*)(ws + OFF_STATE);
  __bf16* encB  = (__bf16*)(ws + OFF_ENC);
  __bf16* hdec  = (__bf16*)(ws + OFF_HDEC);
  __bf16* xall  = (__bf16*)(ws + OFF_XALL);
  __bf16* mf    = (__bf16*)(ws + OFF_MF);
  __bf16* attnS = (__bf16*)(ws + OFF_ATTNS);
  __bf16* hrotE = (__bf16*)(ws + OFF_HROT);
  __bf16* hrotD = hrotE + (size_t)NSLOT_E*BB*HH;
  unsigned* flags = (unsigned*)(ws + OFF_BAR);

  __shared__ float g_lds[4][BB*17];   // per-kq partial gates (64x16, pad 17)
  __shared__ float sc_sh[LL];
  __shared__ float w_sh[LL];

  unsigned bar = 0;
  const int m_ = tid >> 1, q2 = tid & 1;   // elementwise (tid<128)
  const int j0_ = bk*4 + 2*q2;             // this thread's 2 h cols
  const int mt = wv & 3, kq = wv >> 2;
  const int am = mt*16 + l15;
  const int stag = bk >> 3;                // 0..31, distinct per XCD-mate
  const int rotE = stag % 10;
  const int rotD = stag & 15;

  float cfa = 0.f, cfb = 0.f;              // cell state in registers

  // ---- init: zero enc h slot 0 ----
  for (int i = gtid; i < BB*HH/2; i += NB*NT) st_u32_sc((unsigned*)hrotE + i, 0u);
  ++bar; gbar_arrive(flags, bar, bk);

  // ================= encoder: 80 steps, K=1280 4-way split, rotated =========
  for (int t = 0; t < LL; ++t) {
    gbar_wait(flags, bar);
    const __bf16* hR = hrotE + (size_t)t*BB*HH;
    const __bf16* brow = wEnc + (size_t)(bk*16 + l15)*KENC;
    const __bf16* arow = demoC + ((size_t)am*LL + t)*DD;
    const __bf16* hrow = hR + (size_t)am*HH;

    f32x4 acc = {0.f,0.f,0.f,0.f};
#pragma unroll
    for (int i = 0; i < 10; ++i) {
      int idx = i + rotE; if (idx >= 10) idx -= 10;
      int k0 = kq*320 + idx*32 + klane;
      const __bf16* pa = (k0 < DD) ? (arow + k0) : (hrow + (k0 - DD));
      acc = __builtin_amdgcn_mfma_f32_16x16x32_bf16(*(const bf16x8*)pa,
                                                    *(const bf16x8*)(brow + k0), acc, 0,0,0);
    }
    {
      int r0 = mt*16 + lhi*4;
#pragma unroll
      for (int r = 0; r < 4; ++r) g_lds[kq][(r0+r)*17 + l15] = acc[r];
    }
    __syncthreads();
    if (tid < 128) {
      char* hWg = (char*)(hrotE + (size_t)(t+1)*BB*HH);
      int gb = m_*17 + q2*8, cb = bk*16 + q2*8;
      float g[8];
#pragma unroll
      for (int j = 0; j < 8; ++j)
        g[j] = g_lds[0][gb+j] + g_lds[1][gb+j] + g_lds[2][gb+j] + g_lds[3][gb+j] + bE[cb+j];
      float cn0 = sigm(g[1])*cfa + sigm(g[0])*tanhf(g[2]);
      float cn1 = sigm(g[5])*cfb + sigm(g[4])*tanhf(g[6]);
      float hn0 = sigm(g[3])*tanhf(cn0);
      float hn1 = sigm(g[7])*tanhf(cn1);
      cfa = cn0; cfb = cn1;
      unsigned hp = pack_bf16(hn0, hn1);
      st_u32_sc((unsigned*)(hWg + m_*2048 + j0_*2), hp);
      st_u32_sc((unsigned*)(encB + ((size_t)m_*LL + t)*HH + j0_), hp);
    }
    ++bar; gbar_arrive(flags, bar, bk);
  }

  // ================= phase S: static attention + decoder init ===============
  // softmax is h-independent: scores = score_d[b,l] + (h.Wh)[b] -> per-row
  // constant shift cancels. Attn weights shared across all decoder t.
  gbar_wait(flags, bar);
  {
    int b = bk >> 2, qq = bk & 3;
    for (int i = 0; i < 5; ++i) {
      int l = wv*5 + i;
      const __bf16* er = encB + ((size_t)b*LL + l)*HH + ln*16;
      bf16x8 e0 = *(const bf16x8*)(er);
      bf16x8 e1 = *(const bf16x8*)(er + 8);
      float part = 0.f;
#pragma unroll
      for (int j = 0; j < 8; ++j) {
        part += (float)e0[j] * attn_w[ln*16 + j];
        part += (float)e1[j] * attn_w[ln*16 + 8 + j];
      }
      part = wred_sum(part);
      if (ln == 0) sc_sh[l] = part;
    }
    __syncthreads();
    if (wv == 0) {
      int len = demlen[b];
      float s0 = (ln < len) ? sc_sh[ln] : -1e30f;
      float s1 = (ln < 16 && 64+ln < len) ? sc_sh[64+ln] : -1e30f;
      float mx = wred_max(fmaxf(s0, s1));
      float e0 = __expf(s0 - mx);
      float e1 = (ln < 16) ? __expf(s1 - mx) : 0.f;
      float inv = 1.f / wred_sum(e0 + e1);
      w_sh[ln] = e0 * inv;
      if (ln < 16) w_sh[64+ln] = e1 * inv;
    }
    __syncthreads();
    if (tid < 256) {
      int col = qq*256 + tid;
      float a = 0.f;
      const __bf16* eb = encB + (size_t)b*LL*HH + col;
#pragma unroll 4
      for (int l = 0; l < LL; ++l) a += w_sh[l] * (float)eb[(size_t)l*HH];
      st_b16_sc(attnS + (size_t)b*HH + col, a);
    }
    for (int i = gtid; i < BB*HH/2; i += NB*NT) {
      int i2 = i*2;
      st_u32_sc((unsigned*)hrotD + i, pack_bf16(h0[i2], h0[i2+1]));
    }
    if (tid < 128) {
      cfa = c0[m_*HH + j0_];
      cfb = c0[m_*HH + j0_ + 1];
    }
  }
  ++bar; gbar_arrive(flags, bar, bk);

  // ================= phase X: x_all = relu([attn|obs_t]@combW^T + b) ========
  gbar_wait(flags, bar);
  {
    int g = bk*16 + wv;                // 0..4095 waves
    for (int i = 0; i < 3; ++i) {
      int ti = i*4096 + g;             // 0..10239 tiles
      if (ti < 10240) {
        int mtt = ti >> 6, nt = ti & 63;
        f32x4 acc = {0.f,0.f,0.f,0.f};
        const __bf16* brow = wComb + (size_t)(nt*16 + l15)*KCOMB;
        int r = mtt*16 + l15, bb = r & 63;
        const __bf16* aat = attnS + (size_t)bb*HH;
        const __bf16* ast = stateB + (size_t)r*DD;
#pragma unroll 8
        for (int kk = 0; kk < KCOMB; kk += 32) {
          int k0 = kk + klane;
          bf16x8 af = (k0 < HH) ? *(const bf16x8*)(aat + k0)
                                : *(const bf16x8*)(ast + (k0-HH));
          acc = __builtin_amdgcn_mfma_f32_16x16x32_bf16(af, *(const bf16x8*)(brow + k0), acc, 0,0,0);
        }
        int col = nt*16 + l15;
        float cb = comb_b[col];
        int r0 = mtt*16 + lhi*4;
#pragma unroll
        for (int rr = 0; rr < 4; ++rr)
          st_b16_sc(xall + (size_t)(r0+rr)*HH + col, fmaxf(acc[rr]+cb, 0.f));
      }
    }
  }
  ++bar; gbar_arrive(flags, bar, bk);

  // ================= decoder: 40 steps, K=2048 4-way split, rotated =========
  for (int t = 0; t < TT; ++t) {
    gbar_wait(flags, bar);
    const __bf16* hR = hrotD + (size_t)t*BB*HH;
    const __bf16* brow = wLstm + (size_t)(bk*16 + l15)*KLSTM;
    const __bf16* xrow = xall + ((size_t)t*BB + am)*HH;
    const __bf16* hrow = hR + (size_t)am*HH;

    f32x4 acc = {0.f,0.f,0.f,0.f};
#pragma unroll
    for (int i = 0; i < 16; ++i) {
      int idx = (i + rotD) & 15;
      int k0 = kq*512 + idx*32 + klane;
      const __bf16* pa = (k0 < HH) ? (xrow + k0) : (hrow + (k0 - HH));
      acc = __builtin_amdgcn_mfma_f32_16x16x32_bf16(*(const bf16x8*)pa,
                                                    *(const bf16x8*)(brow + k0), acc, 0,0,0);
    }
    {
      int r0 = mt*16 + lhi*4;
#pragma unroll
      for (int r = 0; r < 4; ++r) g_lds[kq][(r0+r)*17 + l15] = acc[r];
    }
    __syncthreads();
    if (tid < 128) {
      char* hWg = (char*)(hrotD + (size_t)(t+1)*BB*HH);
      int gb = m_*17 + q2*8, cb = bk*16 + q2*8;
      float g[8];
#pragma unroll
      for (int j = 0; j < 8; ++j)
        g[j] = g_lds[0][gb+j] + g_lds[1][gb+j] + g_lds[2][gb+j] + g_lds[3][gb+j] + bL[cb+j];
      float cn0 = sigm(g[1])*cfa + sigm(g[0])*tanhf(g[2]);
      float cn1 = sigm(g[5])*cfb + sigm(g[4])*tanhf(g[6]);
      float hn0 = sigm(g[3])*tanhf(cn0);
      float hn1 = sigm(g[7])*tanhf(cn1);
      cfa = cn0; cfb = cn1;
      unsigned hp = pack_bf16(hn0, hn1);
      st_u32_sc((unsigned*)(hWg + m_*2048 + j0_*2), hp);
      st_u32_sc((unsigned*)(hdec + ((size_t)t*BB + m_)*HH + j0_), hp);
      if (t == TT-1) {   // exact fp32 final h from registers
        out[QSZ + m_*HH + j0_]     = hn0;
        out[QSZ + m_*HH + j0_ + 1] = hn1;
      }
    }
    ++bar; gbar_arrive(flags, bar, bk);
  }

  // final c (block-private cols, exact fp32 from registers)
  if (tid < 128) {
    out[QSZ + BB*HH + m_*HH + j0_]     = cfa;
    out[QSZ + BB*HH + m_*HH + j0_ + 1] = cfb;
  }

  // ================= epilogue: m = hdec @ midW^T + mid_b =================
  gbar_wait(flags, bar);
  {
    int g = bk*16 + wv;
    for (int i = 0; i < 3; ++i) {
      int ti = i*4096 + g;
      if (ti < 10240) {
        int mtt = ti >> 6, nt = ti & 63;
        f32x4 acc = {0.f,0.f,0.f,0.f};
        const __bf16* brow = wMid + (size_t)(nt*16 + l15)*HH;
        const __bf16* arow2 = hdec + (size_t)(mtt*16 + l15)*HH;
#pragma unroll 8
        for (int kk = 0; kk < HH; kk += 32) {
          int k0 = kk + klane;
          acc = __builtin_amdgcn_mfma_f32_16x16x32_bf16(*(const bf16x8*)(arow2 + k0),
                                                        *(const bf16x8*)(brow + k0), acc, 0,0,0);
        }
        int col = nt*16 + l15;
        float mb = mid_b[col];
        int r0 = mtt*16 + lhi*4;
#pragma unroll
        for (int rr = 0; rr < 4; ++rr)
          st_b16_sc(mf + (size_t)(r0+rr)*HH + col, acc[rr]+mb);
      }
    }
  }
  ++bar; gbar_arrive(flags, bar, bk);

  // ================= q = mf @ outW^T + out_b =================
  gbar_wait(flags, bar);
  {
    int row = bk*16 + wv;
    if (row < TT*BB) {
      const __bf16* mr = mf + (size_t)row*HH;
      float mreg[16];
#pragma unroll
      for (int k = 0; k < 16; ++k) mreg[k] = (float)mr[ln + 64*k];
      for (int a = 0; a < AA; ++a) {
        float p = 0.f;
#pragma unroll
        for (int k = 0; k < 16; ++k) p += mreg[k] * out_w[(size_t)a*HH + ln + 64*k];
        p = wred_sum(p);
        if (ln == 0) out[(size_t)row*AA + a] = p + out_b[a];
      }
    }
  }
}

// ---------------- host launch ----------------
extern "C" void kernel_launch(void* const* d_in, const int* in_sizes, int n_in,
                              void* d_out, int out_size, void* d_ws, size_t ws_size,
                              hipStream_t stream) {
  (void)in_sizes; (void)n_in; (void)out_size; (void)ws_size;
  const float* state    = (const float*)d_in[0];
  const float* demo     = (const float*)d_in[1];
  const int*   demlen   = (const int*)d_in[2];
  const float* h0       = (const float*)d_in[3];
  const float* c0       = (const float*)d_in[4];
  const float* enc_wih  = (const float*)d_in[5];
  const float* enc_whh  = (const float*)d_in[6];
  const float* enc_bih  = (const float*)d_in[7];
  const float* enc_bhh  = (const float*)d_in[8];
  const float* attn_w   = (const float*)d_in[9];
  const float* comb_w   = (const float*)d_in[11];
  const float* comb_b   = (const float*)d_in[12];
  const float* lstm_wih = (const float*)d_in[13];
  const float* lstm_whh = (const float*)d_in[14];
  const float* lstm_bih = (const float*)d_in[15];
  const float* lstm_bhh = (const float*)d_in[16];
  const float* mid_w    = (const float*)d_in[17];
  const float* mid_b    = (const float*)d_in[18];
  const float* out_w    = (const float*)d_in[19];
  const float* out_b    = (const float*)d_in[20];
  char* ws = (char*)d_ws;

  k_prep<<<PGRID, 256, 0, stream>>>(enc_wih, enc_whh, enc_bih, enc_bhh,
                                    lstm_wih, lstm_whh, lstm_bih, lstm_bhh,
                                    comb_w, mid_w, demo, state, ws);
  k_main<<<NB, NT, 0, stream>>>(demlen, h0, c0, attn_w, comb_b, mid_b,
                                out_w, out_b, (float*)d_out, ws);
}